// Round 6
// baseline (30.504 us; speedup 1.0000x reference)
//
#include <hip/hip_runtime.h>

// Problem constants (fixed by the reference setup)
#define BB 8
#define LL 4096
#define DD 1024
#define KK 2048

#define RPB 16              // output rows per block (4 per wave)
#define NWORDS (LL / 64)    // 64 u64 words per batch bitmap

typedef float f32x4 __attribute__((ext_vector_type(4)));

// Single fused kernel, 1024 blocks x 256 threads (4 blocks/CU).
// Each block:
//  1) rebuilds its batch's 4096-bit boundary bitmap (16 coalesced dword
//     loads + __ballot -> 64 u64 words in LDS; mask is L2-resident),
//  2) wave 0 prefix-scans the 64 popcounts (shfl scan),
//  3) each WAVE binary-searches its own 4 output rows (lanes 0-3, shfl
//     broadcast -- no extra barrier): k-th set bit if k < num_tokens else
//     (k-num_tokens)-th clear bit == stable compaction order of
//     argsort(i + (~bm)*L)[:K] (unique keys),
//  4) copies 4 rows x 4 KiB per wave: 16 independent NT loads per thread
//     (max MLP, per-wave sequential within each row), then 16 NT stores.
__global__ void __launch_bounds__(256)
fused_gather_kernel(const f32x4* __restrict__ src,
                    const int* __restrict__ bm,
                    f32x4* __restrict__ dst,
                    float* __restrict__ om) {
    __shared__ unsigned long long words[NWORDS];
    __shared__ int pre[NWORDS];

    const int blk   = blockIdx.x;          // 0 .. 1023
    const int tid   = threadIdx.x;         // 0 .. 255
    const int lane  = tid & 63;
    const int wave  = tid >> 6;            // 0 .. 3
    const int b     = blk >> 7;            // 128 blocks per batch
    const int kbase = (blk & 127) * RPB;   // k offset within batch

    const int* m = bm + (size_t)b * LL;

    // 1) bitmap: ballot j in wave w covers positions (j*4+w)*64 + lane
#pragma unroll
    for (int j = 0; j < 16; ++j) {
        const unsigned long long w = __ballot(m[j * 256 + tid] != 0);
        if (lane == 0) {
            const int wi = j * 4 + wave;
            words[wi] = w;
            pre[wi]   = __popcll(w);
        }
    }
    __syncthreads();

    // 2) inclusive scan of 64 word-popcounts (wave 0)
    if (wave == 0) {
        int v = pre[lane];
#pragma unroll
        for (int off = 1; off < 64; off <<= 1) {
            const int t = __shfl_up(v, off, 64);
            if (lane >= off) v += t;
        }
        pre[lane] = v;
    }
    __syncthreads();

    const int total = pre[NWORDS - 1];     // num_tokens for batch b

    // next_mask for this block's 16 k's
    if (tid < RPB)
        om[(size_t)b * KK + kbase + tid] = (kbase + tid < total) ? 1.0f : 0.0f;

    // 3) per-wave row selection: lanes 0-3 search, then broadcast
    int srow = 0;
    if (lane < 4) {
        const int kb = kbase + wave * 4 + lane;
        int lo = 0, hi = NWORDS - 1, r;
        unsigned long long x;
        if (kb < total) {
            while (lo < hi) { const int mid = (lo + hi) >> 1; if (pre[mid] > kb) hi = mid; else lo = mid + 1; }
            r = kb - ((lo == 0) ? 0 : pre[lo - 1]);
            x = words[lo];
        } else {
            const int rz = kb - total;
            while (lo < hi) { const int mid = (lo + hi) >> 1; if ((mid + 1) * 64 - pre[mid] > rz) hi = mid; else lo = mid + 1; }
            r = rz - (lo * 64 - ((lo == 0) ? 0 : pre[lo - 1]));
            x = ~words[lo];
        }
        int pos = 0;
#pragma unroll
        for (int sh = 32; sh >= 1; sh >>= 1) {
            const int c = __popcll(x & ((1ull << sh) - 1ull));
            if (r >= c) { r -= c; x >>= sh; pos += sh; }
        }
        srow = lo * 64 + pos;
    }
    int rows[4];
#pragma unroll
    for (int q = 0; q < 4; ++q) rows[q] = __shfl(srow, q, 64);

    // 4) copy: wave handles rows kbase + wave*4 .. +3 (dst contiguous 16 KiB)
    f32x4 v[16];
#pragma unroll
    for (int q = 0; q < 4; ++q) {
        const f32x4* s = src + ((size_t)b * LL + rows[q]) * (DD / 4) + lane;
#pragma unroll
        for (int it = 0; it < 4; ++it)
            v[q * 4 + it] = __builtin_nontemporal_load(&s[it * 64]);
    }
    f32x4* d = dst + ((size_t)b * KK + kbase + wave * 4) * (DD / 4) + lane;
#pragma unroll
    for (int q = 0; q < 4; ++q) {
#pragma unroll
        for (int it = 0; it < 4; ++it)
            __builtin_nontemporal_store(v[q * 4 + it], &d[q * (DD / 4) + it * 64]);
    }
}

extern "C" void kernel_launch(void* const* d_in, const int* in_sizes, int n_in,
                              void* d_out, int out_size, void* d_ws, size_t ws_size,
                              hipStream_t stream) {
    const float* hs = (const float*)d_in[0];   // (B, L, D) f32
    const int*   bm = (const int*)d_in[1];     // (B, L) bool -> int32
    // d_in[2] (mask) unused; d_in[3] (next_max_seqlen) fixed at K=2048

    float* out_hs   = (float*)d_out;                        // B*K*D floats
    float* out_mask = (float*)d_out + (size_t)BB * KK * DD; // B*K floats

    fused_gather_kernel<<<(BB * KK) / RPB, 256, 0, stream>>>(
        (const f32x4*)hs, bm, (f32x4*)out_hs, out_mask);
}